// Round 19
// baseline (583.644 us; speedup 1.0000x reference)
//
#include <hip/hip_runtime.h>

typedef __bf16 bf16x8 __attribute__((ext_vector_type(8)));
typedef float f32x4 __attribute__((ext_vector_type(4)));

#define B_ 2
#define T_ 2048
#define D_ 1024
#define H_ 16

__device__ __forceinline__ ushort f2bf(float f) {
  union { float f; unsigned u; } v; v.f = f;
  unsigned u = v.u;
  return (ushort)((u + 0x7FFFu + ((u >> 16) & 1u)) >> 16);
}
__device__ __forceinline__ float b2f(ushort u) {
  union { unsigned u; float f; } v; v.u = ((unsigned)u) << 16;
  return v.f;
}

// async global->LDS, 16B per lane; LDS dest is wave-uniform base + lane*16
__device__ __forceinline__ void g2l16(const void* g, void* l) {
  __builtin_amdgcn_global_load_lds(
      (const __attribute__((address_space(1))) unsigned int*)g,
      (__attribute__((address_space(3))) unsigned int*)l, 16, 0, 0);
}

// ---------------- cast x -> bf16 ----------------
__global__ __launch_bounds__(256) void cvt_kernel(const float* __restrict__ in,
                                                  ushort* __restrict__ out) {
  int i = (blockIdx.x * 256 + threadIdx.x) * 4;
  float4 v = *(const float4*)(in + i);
  ushort4 o;
  o.x = f2bf(v.x); o.y = f2bf(v.y); o.z = f2bf(v.z); o.w = f2bf(v.w);
  *(ushort4*)(out + i) = o;
}

// ---------------- transpose + cast: in[R][C] f32 -> out[C][R] bf16 ----------------
__global__ void transpose_cvt(const float* __restrict__ in, ushort* __restrict__ out,
                              int R, int C) {
  __shared__ float tile[32][33];
  int bx = blockIdx.x * 32, by = blockIdx.y * 32;
  int tx = threadIdx.x, ty = threadIdx.y;  // block (32,8)
  for (int i = 0; i < 32; i += 8)
    tile[ty + i][tx] = in[(size_t)(by + ty + i) * C + (bx + tx)];
  __syncthreads();
  for (int i = 0; i < 32; i += 8)
    out[(size_t)(bx + ty + i) * R + (by + tx)] = f2bf(tile[tx][ty + i]);
}

// ---------------- bf16 GEMM, f32 out (+bias) ----------------
__global__ __launch_bounds__(256) void gemm_bf16(
    const ushort* __restrict__ A, const ushort* __restrict__ BT,
    float* __restrict__ C, const float* __restrict__ bias,
    int M, int N, int K) {
  __shared__ alignas(16) ushort As[2][4096];
  __shared__ alignas(16) ushort Bs[2][4096];
  int tid = threadIdx.x;
  int wave = tid >> 6, lane = tid & 63;
  int l16 = lane & 15, lhi = lane >> 4;
  int m0 = blockIdx.y * 128, n0 = blockIdx.x * 128;
  int wr = (wave >> 1) * 64, wc = (wave & 1) * 64;
  int srow = lane >> 2, sch = lane & 3;

  f32x4 acc[4][4] = {};

  auto stage = [&](int kk, int buf) {
    for (int i = 0; i < 2; ++i) {
      int rg = i * 4 + wave;
      g2l16(A + (size_t)(m0 + rg * 16 + srow) * K + kk + sch * 8, &As[buf][rg * 512]);
      g2l16(BT + (size_t)(n0 + rg * 16 + srow) * K + kk + sch * 8, &Bs[buf][rg * 512]);
    }
  };

  stage(0, 0);
  int buf = 0;
  for (int kk = 0; kk < K; kk += 32) {
    __syncthreads();
    if (kk + 32 < K) stage(kk + 32, buf ^ 1);
    const ushort* Asb = As[buf];
    const ushort* Bsb = Bs[buf];
    bf16x8 af[4], bfr[4];
    for (int f = 0; f < 4; ++f)
      af[f] = *(const bf16x8*)(Asb + (wr + f * 16 + l16) * 32 + lhi * 8);
    for (int f = 0; f < 4; ++f)
      bfr[f] = *(const bf16x8*)(Bsb + (wc + f * 16 + l16) * 32 + lhi * 8);
    for (int fm = 0; fm < 4; ++fm)
      for (int fn = 0; fn < 4; ++fn)
        acc[fm][fn] = __builtin_amdgcn_mfma_f32_16x16x32_bf16(af[fm], bfr[fn], acc[fm][fn], 0, 0, 0);
    buf ^= 1;
  }
  for (int fm = 0; fm < 4; ++fm)
    for (int fn = 0; fn < 4; ++fn)
      for (int r = 0; r < 4; ++r) {
        int row = m0 + wr + fm * 16 + lhi * 4 + r;
        int col = n0 + wc + fn * 16 + l16;
        float v = acc[fm][fn][r];
        if (bias) v += bias[col];
        C[(size_t)row * N + col] = v;
      }
}

// ---------------- bf16 GEMM, bf16 out (row-major) ----------------
__global__ __launch_bounds__(256) void gemm_bf16_ob(
    const ushort* __restrict__ A, const ushort* __restrict__ BT,
    ushort* __restrict__ C, int M, int N, int K) {
  __shared__ alignas(16) ushort As[2][4096];
  __shared__ alignas(16) ushort Bs[2][4096];
  int tid = threadIdx.x;
  int wave = tid >> 6, lane = tid & 63;
  int l16 = lane & 15, lhi = lane >> 4;
  int m0 = blockIdx.y * 128, n0 = blockIdx.x * 128;
  int wr = (wave >> 1) * 64, wc = (wave & 1) * 64;
  int srow = lane >> 2, sch = lane & 3;

  f32x4 acc[4][4] = {};

  auto stage = [&](int kk, int buf) {
    for (int i = 0; i < 2; ++i) {
      int rg = i * 4 + wave;
      g2l16(A + (size_t)(m0 + rg * 16 + srow) * K + kk + sch * 8, &As[buf][rg * 512]);
      g2l16(BT + (size_t)(n0 + rg * 16 + srow) * K + kk + sch * 8, &Bs[buf][rg * 512]);
    }
  };

  stage(0, 0);
  int buf = 0;
  for (int kk = 0; kk < K; kk += 32) {
    __syncthreads();
    if (kk + 32 < K) stage(kk + 32, buf ^ 1);
    const ushort* Asb = As[buf];
    const ushort* Bsb = Bs[buf];
    bf16x8 af[4], bfr[4];
    for (int f = 0; f < 4; ++f)
      af[f] = *(const bf16x8*)(Asb + (wr + f * 16 + l16) * 32 + lhi * 8);
    for (int f = 0; f < 4; ++f)
      bfr[f] = *(const bf16x8*)(Bsb + (wc + f * 16 + l16) * 32 + lhi * 8);
    for (int fm = 0; fm < 4; ++fm)
      for (int fn = 0; fn < 4; ++fn)
        acc[fm][fn] = __builtin_amdgcn_mfma_f32_16x16x32_bf16(af[fm], bfr[fn], acc[fm][fn], 0, 0, 0);
    buf ^= 1;
  }
  for (int fm = 0; fm < 4; ++fm)
    for (int fn = 0; fn < 4; ++fn)
      for (int r = 0; r < 4; ++r) {
        int row = m0 + wr + fm * 16 + lhi * 4 + r;
        int col = n0 + wc + fn * 16 + l16;
        C[(size_t)row * N + col] = f2bf(acc[fm][fn][r]);
      }
}

// ---------------- build Qaug/Kaug/V from qkvb (bf16, vectorized) ----------------
__global__ __launch_bounds__(256) void augment_kernel(
    const ushort* __restrict__ qkvb,  // [B*T, 3072] bf16
    ushort* __restrict__ Qaug, ushort* __restrict__ Kaug, ushort* __restrict__ Vb) {
  int row = blockIdx.x;  // b*T + t
  int b = row >> 11;
  int t = row & 2047;
  int tid = threadIdx.x;
  const ushort* src = qkvb + (size_t)row * 3072;

  {
    int d4 = tid * 4;
    int h = d4 >> 6, d = d4 & 63;
    size_t obase = ((size_t)(b * H_ + h) * T_ + t);
    ushort4 q = *(const ushort4*)(src + d4);
    ushort4 k = *(const ushort4*)(src + 1024 + d4);
    ushort4 v = *(const ushort4*)(src + 2048 + d4);
    ushort4 qs;
    qs.x = f2bf(b2f(q.x) * 0.125f); qs.y = f2bf(b2f(q.y) * 0.125f);
    qs.z = f2bf(b2f(q.z) * 0.125f); qs.w = f2bf(b2f(q.w) * 0.125f);
    *(ushort4*)(Qaug + obase * 128 + d) = qs;
    *(ushort4*)(Kaug + obase * 128 + d) = k;
    *(ushort4*)(Vb + obase * 64 + d) = v;
  }
  for (int i = 0; i < 2; ++i) {
    int idx = tid + i * 256;
    int h = idx >> 5, mm = idx & 31;
    int gdim = h * 64 + 2 * mm;
    float w = __expf(-9.2103403719761836f * (float)gdim * (1.0f / 1024.0f));
    float ang = w * (float)t;
    float si, co;
    __sincosf(ang, &si, &co);
    ushort2 qp = *(const ushort2*)(src + h * 64 + 2 * mm);
    float qs = b2f(qp.x), qc = b2f(qp.y);
    size_t obase = ((size_t)(b * H_ + h) * T_ + t);
    ushort2 qo, ko;
    qo.x = f2bf((qs * si + qc * co) * 0.125f);
    qo.y = f2bf((qc * si - qs * co) * 0.125f);
    ko.x = f2bf(co);
    ko.y = f2bf(si);
    *(ushort2*)(Qaug + obase * 128 + 64 + 2 * mm) = qo;
    *(ushort2*)(Kaug + obase * 128 + 64 + 2 * mm) = ko;
  }
}

// ---------------- transpose V: [BH, T, 64] -> [BH, 64, T] ----------------
__global__ __launch_bounds__(256) void transpose_v(const ushort* __restrict__ Vb,
                                                   ushort* __restrict__ Vt) {
  __shared__ ushort tile[64][72];
  int bh = blockIdx.y, t0 = blockIdx.x * 64;
  int tid = threadIdx.x;
  for (int i = 0; i < 2; ++i) {
    int e = tid + i * 256;
    int row = e >> 3, ch = e & 7;
    *(int4*)(&tile[row][ch * 8]) =
        *(const int4*)(Vb + ((size_t)bh * T_ + t0 + row) * 64 + ch * 8);
  }
  __syncthreads();
  for (int i = 0; i < 2; ++i) {
    int e = tid + i * 256;
    int d = e >> 3, ch = e & 7;
    union { int4 v; ushort u[8]; } pk;
    for (int u = 0; u < 8; ++u) pk.u[u] = tile[ch * 8 + u][d];
    *(int4*)(Vt + ((size_t)bh * 64 + d) * T_ + t0 + ch * 8) = pk.v;
  }
}

// ---------------- single-QK attention: P tile resident in LDS ----------------
// 16-row q tiles; sweep1 QK^T+exp -> Sbuf (bf16, unnormalized) + plsum;
// in-block reduce -> invl; 2a PV from Sbuf; 2b streaming normalized score write.
__global__ __launch_bounds__(256, 2) void attn_sbuf(
    const ushort* __restrict__ Qaug,  // [BH, T, 128]
    const ushort* __restrict__ Kaug,  // [BH, T, 128]
    const ushort* __restrict__ Vt,    // [BH, 64, T]
    float* __restrict__ score,        // [BH, T, T]
    ushort* __restrict__ ctxb) {      // [B*T, 1024] bf16
  extern __shared__ char dynsmem[];
  ushort* Sbuf  = (ushort*)dynsmem;                   // [16][2048] swizzled, 64 KB
  ushort* Ktile = (ushort*)(dynsmem + 65536);         // 16 KB (sweep1 K tile 64x128)
  ushort* Vtile = (ushort*)(dynsmem + 65536);         // 8 KB (sweep2 V tile 64x64)
  float*  sc    = (float*)(dynsmem + 65536 + 8192);   // 64 row-sum slots

  int flat = blockIdx.y * 128 + blockIdx.x;
  int wg = (flat & 7) * 512 + (flat >> 3);  // XCD chunks: 4 bh per XCD
  int bh = wg >> 7;
  int qt = 127 - (wg & 127);                // big q-tiles first
  int qrow0 = qt * 16;
  int klim = qt >> 2;                       // inclusive last 64-key tile

  int tid = threadIdx.x;
  int wave = tid >> 6, lane = tid & 63;
  int l16 = lane & 15, lhi = lane >> 4, e7 = l16 & 7;

  const ushort* Kbase = Kaug + (size_t)bh * T_ * 128;
  const ushort* Vbase = Vt + (size_t)bh * 64 * T_;

  bf16x8 qf[4];
  {
    const ushort* Qg = Qaug + ((size_t)bh * T_ + qrow0 + l16) * 128;
    for (int ks = 0; ks < 4; ++ks)
      qf[ks] = *(const bf16x8*)(Qg + ks * 32 + lhi * 8);
  }

  // ---- sweep 1: QK^T + exp -> Sbuf, plsum (reg-prefetch K staging) ----
  int4 kreg[4];
  auto loadK = [&](int kt) {
#pragma unroll
    for (int i = 0; i < 4; ++i) {
      int rg = i * 4 + wave;
      int key = rg * 4 + (lane >> 4);
      kreg[i] = *(const int4*)(Kbase + ((size_t)(kt * 64 + key)) * 128 +
                               (((lane & 15) ^ (key & 7)) << 3));
    }
  };
  auto writeK = [&]() {
#pragma unroll
    for (int i = 0; i < 4; ++i)
      *(int4*)(Ktile + (i * 4 + wave) * 512 + lane * 8) = kreg[i];
  };

  loadK(0);
  writeK();
  __syncthreads();
  float plsum[4] = {0.f, 0.f, 0.f, 0.f};
  int keyloc = wave * 16 + l16;  // this wave's key strip within the 64-key tile
  for (int kt = 0; kt <= klim; ++kt) {
    if (kt < klim) loadK(kt + 1);
    __builtin_amdgcn_sched_barrier(0);
    f32x4 s = {};
#pragma unroll
    for (int ks = 0; ks < 4; ++ks) {
      int slot = (ks * 4 + lhi) ^ e7;
      bf16x8 kf = *(const bf16x8*)(Ktile + keyloc * 128 + (slot << 3));
      s = __builtin_amdgcn_mfma_f32_16x16x32_bf16(qf[ks], kf, s, 0, 0, 0);
    }
    if (kt == klim) {
      for (int r = 0; r < 4; ++r)
        if (kt * 64 + keyloc > qrow0 + lhi * 4 + r) s[r] = -1e30f;
    }
    for (int r = 0; r < 4; ++r) {
      float p = __expf(s[r]);
      plsum[r] += p;
      int row_loc = lhi * 4 + r;
      int col = kt * 64 + keyloc;
      Sbuf[row_loc * 2048 + (((col >> 3) ^ (row_loc & 7)) << 3) + (col & 7)] = f2bf(p);
    }
    if (kt < klim) {
      __syncthreads();   // all waves done reading Ktile
      writeK();          // compiler waits on kreg loads
      __syncthreads();   // Ktile(kt+1) visible
    }
  }
  for (int r = 0; r < 4; ++r)
    for (int dd = 1; dd < 16; dd <<= 1)
      plsum[r] += __shfl_xor(plsum[r], dd);
  __syncthreads();  // Ktile reads done; Sbuf fully written
  if (l16 == 0)
    for (int r = 0; r < 4; ++r)
      sc[wave * 16 + lhi * 4 + r] = plsum[r];
  __syncthreads();

  // ---- 2a: PV from Sbuf (V reg-prefetch staging) ----
  int4 vreg[2];
  auto loadV = [&](int kt) {
#pragma unroll
    for (int i = 0; i < 2; ++i) {
      int rg = i * 4 + wave;
      int dim = rg * 8 + (lane >> 3);
      vreg[i] = *(const int4*)(Vbase + (size_t)dim * T_ + kt * 64 +
                               (((lane & 7) ^ (dim & 7)) << 3));
    }
  };
  auto writeV = [&]() {
#pragma unroll
    for (int i = 0; i < 2; ++i)
      *(int4*)(Vtile + (i * 4 + wave) * 512 + lane * 8) = vreg[i];
  };
  loadV(0);
  writeV();
  __syncthreads();
  f32x4 cacc = {};
  int dimloc = wave * 16 + l16;  // this wave's dim strip
  for (int kt = 0; kt <= klim; ++kt) {
    if (kt < klim) loadV(kt + 1);
    __builtin_amdgcn_sched_barrier(0);
#pragma unroll
    for (int ks2 = 0; ks2 < 2; ++ks2) {
      int pslot = (kt * 8 + ks2 * 4 + lhi) ^ e7;  // row = l16, swizzle by row&7 = e7
      bf16x8 pa = *(const bf16x8*)(Sbuf + l16 * 2048 + (pslot << 3));
      int vslot = (ks2 * 4 + lhi) ^ e7;           // dim&7 = l16&7
      bf16x8 vb = *(const bf16x8*)(Vtile + dimloc * 64 + (vslot << 3));
      cacc = __builtin_amdgcn_mfma_f32_16x16x32_bf16(pa, vb, cacc, 0, 0, 0);
    }
    if (kt < klim) {
      __syncthreads();
      writeV();
      __syncthreads();
    }
  }

  // ctx write (normalize with invl)
  {
    int bb = bh >> 4, hh = bh & 15;
    for (int r = 0; r < 4; ++r) {
      int row = lhi * 4 + r;
      float invr = 1.f / (sc[row] + sc[16 + row] + sc[32 + row] + sc[48 + row]);
      int t = qrow0 + row;
      ctxb[((size_t)(bb * T_ + t)) * 1024 + hh * 64 + dimloc] = f2bf(cacc[r] * invr);
    }
  }

  // ---- 2b: streaming normalized score write (+ zero fill beyond lim) ----
  float* srow = score + ((size_t)bh * T_ + qrow0) * T_;
  int lim = (klim + 1) * 64;
  for (int rr = 0; rr < 4; ++rr) {
    int row = wave * 4 + rr;
    float invr = 1.f / (sc[row] + sc[16 + row] + sc[32 + row] + sc[48 + row]);
    float* dst = srow + (size_t)row * T_;
    for (int it = 0; it < 4; ++it) {
      int c = lane + it * 64;
      int c0 = c * 8;
      f32x4 lo = {0.f, 0.f, 0.f, 0.f}, hi = {0.f, 0.f, 0.f, 0.f};
      if (c0 < lim) {
        int4 u = *(const int4*)(Sbuf + row * 2048 + ((c ^ (row & 7)) << 3));
        const ushort* us = (const ushort*)&u;
        lo[0] = b2f(us[0]) * invr; lo[1] = b2f(us[1]) * invr;
        lo[2] = b2f(us[2]) * invr; lo[3] = b2f(us[3]) * invr;
        hi[0] = b2f(us[4]) * invr; hi[1] = b2f(us[5]) * invr;
        hi[2] = b2f(us[6]) * invr; hi[3] = b2f(us[7]) * invr;
      }
      *(f32x4*)(dst + c0) = lo;
      *(f32x4*)(dst + c0 + 4) = hi;
    }
  }
}

extern "C" void kernel_launch(void* const* d_in, const int* in_sizes, int n_in,
                              void* d_out, int out_size, void* d_ws, size_t ws_size,
                              hipStream_t stream) {
  const float* x    = (const float*)d_in[0];
  const float* Wqkv = (const float*)d_in[2];
  const float* Wout = (const float*)d_in[3];
  const float* bout = (const float*)d_in[4];

  char* ws = (char*)d_ws;
  ushort* xb    = (ushort*)(ws + 0);           //  8 MB
  ushort* wqkvT = (ushort*)(ws + 8388608);     //  6 MB
  ushort* woutT = (ushort*)(ws + 14680064);    //  2 MB
  ushort* qkvb  = (ushort*)(ws + 16777216);    // 24 MB bf16 [B*T,3072]
  ushort* Qaug  = (ushort*)(ws + 50331648);    // 16 MB
  ushort* Kaug  = (ushort*)(ws + 67108864);    // 16 MB
  ushort* Vb    = (ushort*)(ws + 83886080);    //  8 MB
  ushort* Vt    = (ushort*)(ws + 92274688);    //  8 MB
  ushort* ctxb  = (ushort*)(ws + 100663296);   //  8 MB

  float* out   = (float*)d_out;
  float* score = out + (size_t)4194304;  // B*T*D floats, then [B,H,T,T]

  static bool attr_set = false;
  (void)attr_set;
  hipFuncSetAttribute((const void*)attn_sbuf,
                      hipFuncAttributeMaxDynamicSharedMemorySize, 81920);

  cvt_kernel<<<4096, 256, 0, stream>>>(x, xb);
  dim3 tb(32, 8);
  transpose_cvt<<<dim3(3072 / 32, 1024 / 32), tb, 0, stream>>>(Wqkv, wqkvT, 1024, 3072);
  transpose_cvt<<<dim3(1024 / 32, 1024 / 32), tb, 0, stream>>>(Wout, woutT, 1024, 1024);
  gemm_bf16_ob<<<dim3(24, 32), 256, 0, stream>>>(xb, wqkvT, qkvb, 4096, 3072, 1024);
  augment_kernel<<<4096, 256, 0, stream>>>(qkvb, Qaug, Kaug, Vb);
  transpose_v<<<dim3(32, 32), 256, 0, stream>>>(Vb, Vt);
  attn_sbuf<<<dim3(128, 32), 256, 81920, stream>>>(Qaug, Kaug, Vt, score, ctxb);
  gemm_bf16<<<dim3(8, 32), 256, 0, stream>>>(ctxb, woutT, out, bout, 4096, 1024, 1024);
}

// Round 20
// 314.772 us; speedup vs baseline: 1.8542x; 1.8542x over previous
//
#include <hip/hip_runtime.h>

typedef __bf16 bf16x8 __attribute__((ext_vector_type(8)));
typedef float f32x4 __attribute__((ext_vector_type(4)));
typedef float f32x16 __attribute__((ext_vector_type(16)));

#define B_ 2
#define T_ 2048
#define D_ 1024
#define H_ 16

__device__ __forceinline__ ushort f2bf(float f) {
  union { float f; unsigned u; } v; v.f = f;
  unsigned u = v.u;
  return (ushort)((u + 0x7FFFu + ((u >> 16) & 1u)) >> 16);
}
__device__ __forceinline__ float b2f(ushort u) {
  union { unsigned u; float f; } v; v.u = ((unsigned)u) << 16;
  return v.f;
}

// async global->LDS, 16B per lane; LDS dest is wave-uniform base + lane*16
__device__ __forceinline__ void g2l16(const void* g, void* l) {
  __builtin_amdgcn_global_load_lds(
      (const __attribute__((address_space(1))) unsigned int*)g,
      (__attribute__((address_space(3))) unsigned int*)l, 16, 0, 0);
}

// ---------------- cast x -> bf16 ----------------
__global__ __launch_bounds__(256) void cvt_kernel(const float* __restrict__ in,
                                                  ushort* __restrict__ out) {
  int i = (blockIdx.x * 256 + threadIdx.x) * 4;
  float4 v = *(const float4*)(in + i);
  ushort4 o;
  o.x = f2bf(v.x); o.y = f2bf(v.y); o.z = f2bf(v.z); o.w = f2bf(v.w);
  *(ushort4*)(out + i) = o;
}

// ---------------- transpose + cast: in[R][C] f32 -> out[C][R] bf16 ----------------
__global__ void transpose_cvt(const float* __restrict__ in, ushort* __restrict__ out,
                              int R, int C) {
  __shared__ float tile[32][33];
  int bx = blockIdx.x * 32, by = blockIdx.y * 32;
  int tx = threadIdx.x, ty = threadIdx.y;  // block (32,8)
  for (int i = 0; i < 32; i += 8)
    tile[ty + i][tx] = in[(size_t)(by + ty + i) * C + (bx + tx)];
  __syncthreads();
  for (int i = 0; i < 32; i += 8)
    out[(size_t)(bx + ty + i) * R + (by + tx)] = f2bf(tile[tx][ty + i]);
}

// ---------------- bf16 GEMM, f32 out (+bias) ----------------
__global__ __launch_bounds__(256) void gemm_bf16(
    const ushort* __restrict__ A, const ushort* __restrict__ BT,
    float* __restrict__ C, const float* __restrict__ bias,
    int M, int N, int K) {
  __shared__ alignas(16) ushort As[2][4096];
  __shared__ alignas(16) ushort Bs[2][4096];
  int tid = threadIdx.x;
  int wave = tid >> 6, lane = tid & 63;
  int l16 = lane & 15, lhi = lane >> 4;
  int m0 = blockIdx.y * 128, n0 = blockIdx.x * 128;
  int wr = (wave >> 1) * 64, wc = (wave & 1) * 64;
  int srow = lane >> 2, sch = lane & 3;

  f32x4 acc[4][4] = {};

  auto stage = [&](int kk, int buf) {
    for (int i = 0; i < 2; ++i) {
      int rg = i * 4 + wave;
      g2l16(A + (size_t)(m0 + rg * 16 + srow) * K + kk + sch * 8, &As[buf][rg * 512]);
      g2l16(BT + (size_t)(n0 + rg * 16 + srow) * K + kk + sch * 8, &Bs[buf][rg * 512]);
    }
  };

  stage(0, 0);
  int buf = 0;
  for (int kk = 0; kk < K; kk += 32) {
    __syncthreads();
    if (kk + 32 < K) stage(kk + 32, buf ^ 1);
    const ushort* Asb = As[buf];
    const ushort* Bsb = Bs[buf];
    bf16x8 af[4], bfr[4];
    for (int f = 0; f < 4; ++f)
      af[f] = *(const bf16x8*)(Asb + (wr + f * 16 + l16) * 32 + lhi * 8);
    for (int f = 0; f < 4; ++f)
      bfr[f] = *(const bf16x8*)(Bsb + (wc + f * 16 + l16) * 32 + lhi * 8);
    for (int fm = 0; fm < 4; ++fm)
      for (int fn = 0; fn < 4; ++fn)
        acc[fm][fn] = __builtin_amdgcn_mfma_f32_16x16x32_bf16(af[fm], bfr[fn], acc[fm][fn], 0, 0, 0);
    buf ^= 1;
  }
  for (int fm = 0; fm < 4; ++fm)
    for (int fn = 0; fn < 4; ++fn)
      for (int r = 0; r < 4; ++r) {
        int row = m0 + wr + fm * 16 + lhi * 4 + r;
        int col = n0 + wc + fn * 16 + l16;
        float v = acc[fm][fn][r];
        if (bias) v += bias[col];
        C[(size_t)row * N + col] = v;
      }
}

// ---------------- bf16 GEMM, bf16 out (row-major, line-assembled stores) ----------------
__global__ __launch_bounds__(256) void gemm_bf16_ob(
    const ushort* __restrict__ A, const ushort* __restrict__ BT,
    ushort* __restrict__ C, int M, int N, int K) {
  __shared__ alignas(16) ushort As[2][4096];
  __shared__ alignas(16) ushort Bs[2][4096];
  int tid = threadIdx.x;
  int wave = tid >> 6, lane = tid & 63;
  int l16 = lane & 15, lhi = lane >> 4;
  int m0 = blockIdx.y * 128, n0 = blockIdx.x * 128;
  int wr = (wave >> 1) * 64, wc = (wave & 1) * 64;
  int srow = lane >> 2, sch = lane & 3;

  f32x4 acc[4][4] = {};

  auto stage = [&](int kk, int buf) {
    for (int i = 0; i < 2; ++i) {
      int rg = i * 4 + wave;
      g2l16(A + (size_t)(m0 + rg * 16 + srow) * K + kk + sch * 8, &As[buf][rg * 512]);
      g2l16(BT + (size_t)(n0 + rg * 16 + srow) * K + kk + sch * 8, &Bs[buf][rg * 512]);
    }
  };

  stage(0, 0);
  int buf = 0;
  for (int kk = 0; kk < K; kk += 32) {
    __syncthreads();
    if (kk + 32 < K) stage(kk + 32, buf ^ 1);
    const ushort* Asb = As[buf];
    const ushort* Bsb = Bs[buf];
    bf16x8 af[4], bfr[4];
    for (int f = 0; f < 4; ++f)
      af[f] = *(const bf16x8*)(Asb + (wr + f * 16 + l16) * 32 + lhi * 8);
    for (int f = 0; f < 4; ++f)
      bfr[f] = *(const bf16x8*)(Bsb + (wc + f * 16 + l16) * 32 + lhi * 8);
    for (int fm = 0; fm < 4; ++fm)
      for (int fn = 0; fn < 4; ++fn)
        acc[fm][fn] = __builtin_amdgcn_mfma_f32_16x16x32_bf16(af[fm], bfr[fn], acc[fm][fn], 0, 0, 0);
    buf ^= 1;
  }
  for (int fm = 0; fm < 4; ++fm)
    for (int fn = 0; fn < 4; ++fn)
      for (int r = 0; r < 4; ++r) {
        int row = m0 + wr + fm * 16 + lhi * 4 + r;
        int col = n0 + wc + fn * 16 + l16;
        C[(size_t)row * N + col] = f2bf(acc[fm][fn][r]);
      }
}

// ---------------- build Qaug/Kaug/V from qkvb (bf16, vectorized) ----------------
__global__ __launch_bounds__(256) void augment_kernel(
    const ushort* __restrict__ qkvb,  // [B*T, 3072] bf16
    ushort* __restrict__ Qaug, ushort* __restrict__ Kaug, ushort* __restrict__ Vb) {
  int row = blockIdx.x;  // b*T + t
  int b = row >> 11;
  int t = row & 2047;
  int tid = threadIdx.x;
  const ushort* src = qkvb + (size_t)row * 3072;

  // base parts: thread handles 4 consecutive bf16 per slice (ushort4 in/out)
  {
    int d4 = tid * 4;             // 0..1020
    int h = d4 >> 6, d = d4 & 63;
    size_t obase = ((size_t)(b * H_ + h) * T_ + t);
    ushort4 q = *(const ushort4*)(src + d4);
    ushort4 k = *(const ushort4*)(src + 1024 + d4);
    ushort4 v = *(const ushort4*)(src + 2048 + d4);
    ushort4 qs;  // *0.125 = exponent-3: exact on bf16 (mantissa unchanged)
    qs.x = f2bf(b2f(q.x) * 0.125f); qs.y = f2bf(b2f(q.y) * 0.125f);
    qs.z = f2bf(b2f(q.z) * 0.125f); qs.w = f2bf(b2f(q.w) * 0.125f);
    *(ushort4*)(Qaug + obase * 128 + d) = qs;
    *(ushort4*)(Kaug + obase * 128 + d) = k;
    *(ushort4*)(Vb + obase * 64 + d) = v;
  }
  // trig parts: 512 slots = 16 h x 32 mm
  for (int i = 0; i < 2; ++i) {
    int idx = tid + i * 256;
    int h = idx >> 5, mm = idx & 31;
    int gdim = h * 64 + 2 * mm;
    float w = __expf(-9.2103403719761836f * (float)gdim * (1.0f / 1024.0f));
    float ang = w * (float)t;
    float si, co;
    __sincosf(ang, &si, &co);
    ushort2 qp = *(const ushort2*)(src + h * 64 + 2 * mm);
    float qs = b2f(qp.x), qc = b2f(qp.y);
    size_t obase = ((size_t)(b * H_ + h) * T_ + t);
    ushort2 qo, ko;
    qo.x = f2bf((qs * si + qc * co) * 0.125f);
    qo.y = f2bf((qc * si - qs * co) * 0.125f);
    ko.x = f2bf(co);
    ko.y = f2bf(si);
    *(ushort2*)(Qaug + obase * 128 + 64 + 2 * mm) = qo;
    *(ushort2*)(Kaug + obase * 128 + 64 + 2 * mm) = ko;
  }
}

// ---------------- transpose V: [BH, T, 64] -> [BH, 64, T] ----------------
__global__ __launch_bounds__(256) void transpose_v(const ushort* __restrict__ Vb,
                                                   ushort* __restrict__ Vt) {
  __shared__ ushort tile[64][72];
  int bh = blockIdx.y, t0 = blockIdx.x * 64;
  int tid = threadIdx.x;
  for (int i = 0; i < 2; ++i) {
    int e = tid + i * 256;
    int row = e >> 3, ch = e & 7;
    *(int4*)(&tile[row][ch * 8]) =
        *(const int4*)(Vb + ((size_t)bh * T_ + t0 + row) * 64 + ch * 8);
  }
  __syncthreads();
  for (int i = 0; i < 2; ++i) {
    int e = tid + i * 256;
    int d = e >> 3, ch = e & 7;
    union { int4 v; ushort u[8]; } pk;
    for (int u = 0; u < 8; ++u) pk.u[u] = tile[ch * 8 + u][d];
    *(int4*)(Vt + ((size_t)bh * 64 + d) * T_ + t0 + ch * 8) = pk.v;
  }
}

// row-within-32 for 32x32 MFMA C/D layout
__device__ __forceinline__ int rowf32(int reg, int hi) {
  return (reg & 3) + 8 * (reg >> 2) + 4 * hi;
}

// ---------------- denominator kernel: 32x32 MFMA, quadrant waves ----------------
__global__ __launch_bounds__(256, 4) void denom_kernel(
    const ushort* __restrict__ Qaug,  // [BH, T, 128]
    const ushort* __restrict__ Kaug,  // [BH, T, 128]
    float* __restrict__ invlb) {      // [BH, T]
  int flat = blockIdx.y * 32 + blockIdx.x;
  int wg = (flat & 7) * 128 + (flat >> 3);
  int bh = wg >> 5;
  int qt = 31 - (wg & 31);
  int tid = threadIdx.x;
  int wave = tid >> 6, lane = tid & 63;
  int l31 = lane & 31, hi = lane >> 5;
  int r = wave >> 1, d = wave & 1;

  __shared__ alignas(16) ushort Ks[2][8192];  // [key 0..63][128], chunk^(key&15)
  __shared__ float sums[64];

  const ushort* Kbase = Kaug + (size_t)bh * T_ * 128;

  auto stageK = [&](int kt, int buf) {
    for (int i = 0; i < 4; ++i) {
      int rg = i * 4 + wave;
      int key = rg * 4 + (lane >> 4);
      const ushort* g = Kbase + ((size_t)(kt * 64 + key)) * 128 + (((lane & 15) ^ (key & 15)) << 3);
      g2l16(g, &Ks[buf][rg * 512]);
    }
  };

  bf16x8 qf[8];
  {
    const ushort* Qg = Qaug + ((size_t)bh * T_ + qt * 64 + r * 32 + l31) * 128;
    for (int ks = 0; ks < 8; ++ks)
      qf[ks] = *(const bf16x8*)(Qg + ks * 16 + hi * 8);
  }
  int key = d * 32 + l31;

  stageK(0, 0);
  asm volatile("s_waitcnt vmcnt(0)" ::: "memory");
  __builtin_amdgcn_s_barrier();
  float plsum[16];
  for (int i = 0; i < 16; ++i) plsum[i] = 0.f;

  for (int kt = 0; kt <= qt; ++kt) {
    int buf = kt & 1;
    if (kt < qt) stageK(kt + 1, buf ^ 1);
    __builtin_amdgcn_sched_barrier(0);
    const ushort* Kb = Ks[buf];
    f32x16 s = {};
    for (int ks = 0; ks < 8; ++ks) {
      int slot = (ks * 2 + hi) ^ (key & 15);
      bf16x8 kf = *(const bf16x8*)(Kb + key * 128 + (slot << 3));
      s = __builtin_amdgcn_mfma_f32_32x32x16_bf16(qf[ks], kf, s, 0, 0, 0);
    }
    if (kt == qt) {
      for (int reg = 0; reg < 16; ++reg)
        if (d * 32 + l31 > r * 32 + rowf32(reg, hi)) s[reg] = -1e30f;
    }
    for (int reg = 0; reg < 16; ++reg) plsum[reg] += __expf(s[reg]);
    if (kt < qt) {
      asm volatile("s_waitcnt vmcnt(0)" ::: "memory");
      __builtin_amdgcn_s_barrier();
    }
  }
  for (int reg = 0; reg < 16; ++reg) {
    float v = plsum[reg];
    for (int dd = 1; dd < 32; dd <<= 1) v += __shfl_xor(v, dd);
    plsum[reg] = v;
  }
  if (d == 1 && l31 == 0)
    for (int reg = 0; reg < 16; ++reg)
      sums[r * 32 + rowf32(reg, hi)] = plsum[reg];
  __syncthreads();
  if (d == 0 && l31 == 0)
    for (int reg = 0; reg < 16; ++reg) {
      int row = r * 32 + rowf32(reg, hi);
      invlb[(size_t)bh * T_ + qt * 64 + row] = 1.f / (plsum[reg] + sums[row]);
    }
}

// ---------------- attention main: 32x32 MFMA, quadrant waves ----------------
__global__ __launch_bounds__(256) void attn2_kernel(
    const ushort* __restrict__ Qaug,  // [BH, T, 128]
    const ushort* __restrict__ Kaug,  // [BH, T, 128]
    const ushort* __restrict__ Vt,    // [BH, 64, T]
    const float* __restrict__ invlb,  // [BH, T]
    float* __restrict__ score,        // [BH, T, T]
    ushort* __restrict__ ctxb) {      // [B*T, 1024] bf16
  int flat = blockIdx.y * 32 + blockIdx.x;
  int wg = (flat & 7) * 128 + (flat >> 3);
  int bh = wg >> 5;
  int qt = 31 - (wg & 31);
  int tid = threadIdx.x;
  int wave = tid >> 6, lane = tid & 63;
  int l31 = lane & 31, hi = lane >> 5;
  int r = wave >> 1, d = wave & 1;

  __shared__ alignas(16) ushort Ks[2][8192];  // [key][128], chunk^(key&15)
  __shared__ alignas(16) ushort Vs[2][4096];  // [dim][64 keys], chunk^(dim&7)
  __shared__ alignas(16) ushort Ps[4096];     // [qrow][64 keys], chunk^(row&7)

  const ushort* Kbase = Kaug + (size_t)bh * T_ * 128;
  const ushort* Vbase = Vt + (size_t)bh * 64 * T_;

  auto stageK = [&](int kt, int buf) {
    for (int i = 0; i < 4; ++i) {
      int rg = i * 4 + wave;
      int key = rg * 4 + (lane >> 4);
      const ushort* g = Kbase + ((size_t)(kt * 64 + key)) * 128 + (((lane & 15) ^ (key & 15)) << 3);
      g2l16(g, &Ks[buf][rg * 512]);
    }
  };
  auto stageV = [&](int kt, int buf) {
    for (int i = 0; i < 2; ++i) {
      int rg = i * 4 + wave;
      int dim = rg * 8 + (lane >> 3);
      const ushort* g = Vbase + (size_t)dim * T_ + kt * 64 + (((lane & 7) ^ (dim & 7)) << 3);
      g2l16(g, &Vs[buf][rg * 512]);
    }
  };

  bf16x8 qf[8];
  {
    const ushort* Qg = Qaug + ((size_t)bh * T_ + qt * 64 + r * 32 + l31) * 128;
    for (int ks = 0; ks < 8; ++ks)
      qf[ks] = *(const bf16x8*)(Qg + ks * 16 + hi * 8);
  }
  int key = d * 32 + l31;
  float4 iv[4];
  for (int g = 0; g < 4; ++g)
    iv[g] = *(const float4*)(invlb + (size_t)bh * T_ + qt * 64 + r * 32 + hi * 4 + g * 8);

  stageK(0, 0);
  stageV(0, 0);
  asm volatile("s_waitcnt vmcnt(0)" ::: "memory");
  __builtin_amdgcn_s_barrier();
  f32x16 cacc[2] = {};
  float* srow = score + ((size_t)bh * T_ + (size_t)qt * 64) * T_;

  for (int kt = 0; kt <= qt; ++kt) {
    int buf = kt & 1;
    if (kt < qt) { stageK(kt + 1, buf ^ 1); stageV(kt + 1, buf ^ 1); }
    __builtin_amdgcn_sched_barrier(0);
    const ushort* Kb = Ks[buf];
    f32x16 s = {};
    for (int ks = 0; ks < 8; ++ks) {
      int slot = (ks * 2 + hi) ^ (key & 15);
      bf16x8 kf = *(const bf16x8*)(Kb + key * 128 + (slot << 3));
      s = __builtin_amdgcn_mfma_f32_32x32x16_bf16(qf[ks], kf, s, 0, 0, 0);
    }
    if (kt == qt) {
      for (int reg = 0; reg < 16; ++reg)
        if (d * 32 + l31 > r * 32 + rowf32(reg, hi)) s[reg] = -1e30f;
    }
    for (int reg = 0; reg < 16; ++reg) {
      int row_loc = r * 32 + rowf32(reg, hi);
      float p = __expf(s[reg]) * iv[reg >> 2][reg & 3];
      srow[(size_t)row_loc * T_ + kt * 64 + key] = p;
      Ps[row_loc * 64 + ((((key >> 3)) ^ (row_loc & 7)) << 3) + (key & 7)] = f2bf(p);
    }
    asm volatile("s_waitcnt lgkmcnt(0)" ::: "memory");
    __builtin_amdgcn_sched_barrier(0);
    const ushort* Vb2 = Vs[buf];
    int rowA = r * 32 + l31;
    for (int ks2 = 0; ks2 < 2; ++ks2) {
      int chunkA = d * 4 + ks2 * 2 + hi;
      bf16x8 pa = *(const bf16x8*)(Ps + rowA * 64 + ((chunkA ^ (rowA & 7)) << 3));
      for (int b2 = 0; b2 < 2; ++b2) {
        int dim = b2 * 32 + l31;
        bf16x8 vb = *(const bf16x8*)(Vb2 + dim * 64 + ((chunkA ^ (dim & 7)) << 3));
        cacc[b2] = __builtin_amdgcn_mfma_f32_32x32x16_bf16(pa, vb, cacc[b2], 0, 0, 0);
      }
    }
    if (kt < qt) {
      asm volatile("s_waitcnt vmcnt(16)" ::: "memory");
      __builtin_amdgcn_s_barrier();
    }
  }

  // zero-fill upper-triangle tiles of score
  {
    int row = tid >> 2, c16 = (tid & 3) * 16;
    f32x4 z = {0.f, 0.f, 0.f, 0.f};
    for (int kt = qt + 1; kt < 32; ++kt) {
      f32x4* dst = (f32x4*)(srow + (size_t)row * T_ + kt * 64 + c16);
      for (int u = 0; u < 4; ++u) dst[u] = z;
    }
  }

  // combine key-half partial ctx across wave pairs, write ctxb
  __builtin_amdgcn_s_barrier();
  float* xch = (float*)Ks;
  if (d == 1) {
    for (int b2 = 0; b2 < 2; ++b2)
      for (int reg = 0; reg < 16; ++reg)
        xch[(r * 32 + rowf32(reg, hi)) * 64 + b2 * 32 + l31] = cacc[b2][reg];
  }
  __syncthreads();
  if (d == 0) {
    int b = bh >> 4, h = bh & 15;
    for (int b2 = 0; b2 < 2; ++b2)
      for (int reg = 0; reg < 16; ++reg) {
        int row_loc = r * 32 + rowf32(reg, hi);
        float v = cacc[b2][reg] + xch[row_loc * 64 + b2 * 32 + l31];
        int t = qt * 64 + row_loc;
        ctxb[((size_t)(b * T_ + t)) * 1024 + h * 64 + b2 * 32 + l31] = f2bf(v);
      }
  }
}

extern "C" void kernel_launch(void* const* d_in, const int* in_sizes, int n_in,
                              void* d_out, int out_size, void* d_ws, size_t ws_size,
                              hipStream_t stream) {
  const float* x    = (const float*)d_in[0];
  const float* Wqkv = (const float*)d_in[2];
  const float* Wout = (const float*)d_in[3];
  const float* bout = (const float*)d_in[4];

  char* ws = (char*)d_ws;
  ushort* xb    = (ushort*)(ws + 0);           //  8 MB
  ushort* wqkvT = (ushort*)(ws + 8388608);     //  6 MB
  ushort* woutT = (ushort*)(ws + 14680064);    //  2 MB
  ushort* qkvb  = (ushort*)(ws + 16777216);    // 24 MB bf16 [B*T,3072]
  ushort* Qaug  = (ushort*)(ws + 50331648);    // 16 MB
  ushort* Kaug  = (ushort*)(ws + 67108864);    // 16 MB
  ushort* Vb    = (ushort*)(ws + 83886080);    //  8 MB
  ushort* Vt    = (ushort*)(ws + 92274688);    //  8 MB
  ushort* ctxb  = (ushort*)(ws + 100663296);   //  8 MB
  float*  invlb = (float*) (ws + 109051904);   // 256 KB

  float* out   = (float*)d_out;
  float* score = out + (size_t)4194304;  // B*T*D floats, then [B,H,T,T]

  cvt_kernel<<<4096, 256, 0, stream>>>(x, xb);
  dim3 tb(32, 8);
  transpose_cvt<<<dim3(3072 / 32, 1024 / 32), tb, 0, stream>>>(Wqkv, wqkvT, 1024, 3072);
  transpose_cvt<<<dim3(1024 / 32, 1024 / 32), tb, 0, stream>>>(Wout, woutT, 1024, 1024);
  gemm_bf16_ob<<<dim3(24, 32), 256, 0, stream>>>(xb, wqkvT, qkvb, 4096, 3072, 1024);
  augment_kernel<<<4096, 256, 0, stream>>>(qkvb, Qaug, Kaug, Vb);
  transpose_v<<<dim3(32, 32), 256, 0, stream>>>(Vb, Vt);
  denom_kernel<<<dim3(32, 32), 256, 0, stream>>>(Qaug, Kaug, invlb);
  attn2_kernel<<<dim3(32, 32), 256, 0, stream>>>(Qaug, Kaug, Vt, invlb, score, ctxb);
  gemm_bf16<<<dim3(8, 32), 256, 0, stream>>>(ctxb, woutT, out, bout, 4096, 1024, 1024);
}